// Round 1
// baseline (224.298 us; speedup 1.0000x reference)
//
#include <hip/hip_runtime.h>
#include <math.h>

#define VOCAB 50257
#define EMB   128
#define CTX   200

// ---------------- K1: s[v] = sum_t X[t,v]  (X is [CTX, VOCAB] row-major) ----
// grid (197, 8), block 256. Each block sums 25 rows for its 256-column slab,
// then one float atomicAdd per element into zero-initialized s.
__global__ void k_colsum(const float* __restrict__ X, float* __restrict__ s) {
    int v = blockIdx.x * blockDim.x + threadIdx.x;
    if (v >= VOCAB) return;
    const int rows = CTX / 8;                 // 25
    int t0 = blockIdx.y * rows;
    const float* p = X + (size_t)t0 * VOCAB + v;
    float a0 = 0.f, a1 = 0.f, a2 = 0.f, a3 = 0.f, a4 = 0.f;
#pragma unroll
    for (int i = 0; i < 5; ++i) {
        a0 += p[0 * VOCAB];
        a1 += p[1 * VOCAB];
        a2 += p[2 * VOCAB];
        a3 += p[3 * VOCAB];
        a4 += p[4 * VOCAB];
        p += 5 * VOCAB;
    }
    atomicAdd(&s[v], ((a0 + a1) + (a2 + a3)) + a4);
}

// ---------------- K2: hraw[e] = sum_v s[v] * Wq[e,v] ------------------------
// grid (32, 128), block 256. blockIdx.y = e. Block-reduce, one atomic per block.
__global__ void k_hidden(const float* __restrict__ Wq, const float* __restrict__ s,
                         float* __restrict__ hraw) {
    int e = blockIdx.y;
    const float* row = Wq + (size_t)e * VOCAB;
    float acc = 0.f;
    int stride = gridDim.x * blockDim.x;      // 8192
    for (int v = blockIdx.x * blockDim.x + threadIdx.x; v < VOCAB; v += stride)
        acc += s[v] * row[v];
    // wave reduce (64 lanes)
    for (int off = 32; off > 0; off >>= 1) acc += __shfl_down(acc, off, 64);
    __shared__ float wsum[4];
    int lane = threadIdx.x & 63, wid = threadIdx.x >> 6;
    if (lane == 0) wsum[wid] = acc;
    __syncthreads();
    if (threadIdx.x == 0)
        atomicAdd(&hraw[e], (wsum[0] + wsum[1]) + (wsum[2] + wsum[3]));
}

// ---------------- K3: logits[v] = dot(hidden, Ww[v,:]) + bw[v]; gsum += exp --
// hidden[e] = (hraw[e] + CTX*bq[e]) / length, built once per block in LDS.
// 16 lanes per row v; each lane covers 8 consecutive e via two float4 loads.
// grid (ceil(VOCAB/16)), block 256 -> 16 rows/block, 8 KB contiguous per block.
__global__ void k_logits(const float* __restrict__ Ww, const float* __restrict__ bw,
                         const float* __restrict__ hraw, const float* __restrict__ bq,
                         const int* __restrict__ lenp,
                         float* __restrict__ logits, float* __restrict__ gsum) {
    __shared__ float h[EMB];
    __shared__ float wsum[4];
    if (threadIdx.x < EMB) {
        float len = (float)lenp[0];
        h[threadIdx.x] = (hraw[threadIdx.x] + (float)CTX * bq[threadIdx.x]) / len;
    }
    __syncthreads();

    int group = threadIdx.x >> 4;             // 0..15
    int c     = threadIdx.x & 15;             // lane within group
    int v     = blockIdx.x * 16 + group;
    bool valid = (v < VOCAB);

    float acc = 0.f;
    if (valid) {
        const float4* row = (const float4*)(Ww + (size_t)v * EMB);
        float4 w0 = row[c * 2];
        float4 w1 = row[c * 2 + 1];
        const float* hp = h + c * 8;
        acc = w0.x * hp[0] + w0.y * hp[1] + w0.z * hp[2] + w0.w * hp[3]
            + w1.x * hp[4] + w1.y * hp[5] + w1.z * hp[6] + w1.w * hp[7];
    }
    // reduce within 16-lane group (xor stays inside the group)
    acc += __shfl_xor(acc, 1, 64);
    acc += __shfl_xor(acc, 2, 64);
    acc += __shfl_xor(acc, 4, 64);
    acc += __shfl_xor(acc, 8, 64);

    float myexp = 0.f;
    if (valid && c == 0) {
        float logit = acc + bw[v];
        logits[v] = logit;
        myexp = expf(logit);
    }
    // block reduce of exp contributions, one atomic per block
    float ssum = myexp;
    for (int off = 32; off > 0; off >>= 1) ssum += __shfl_down(ssum, off, 64);
    int lane = threadIdx.x & 63, wid = threadIdx.x >> 6;
    if (lane == 0) wsum[wid] = ssum;
    __syncthreads();
    if (threadIdx.x == 0)
        atomicAdd(gsum, (wsum[0] + wsum[1]) + (wsum[2] + wsum[3]));
}

// ---------------- K4: out[v] = logits[v] - log(gsum) ------------------------
__global__ void k_finalize(const float* __restrict__ logits,
                           const float* __restrict__ gsum,
                           float* __restrict__ out) {
    int v = blockIdx.x * blockDim.x + threadIdx.x;
    if (v < VOCAB) out[v] = logits[v] - logf(gsum[0]);
}

extern "C" void kernel_launch(void* const* d_in, const int* in_sizes, int n_in,
                              void* d_out, int out_size, void* d_ws, size_t ws_size,
                              hipStream_t stream) {
    const float* X    = (const float*)d_in[0];   // [CTX, VOCAB]
    const int*   lenp = (const int*)d_in[1];     // scalar 200
    const float* Wq   = (const float*)d_in[2];   // [EMB, VOCAB]
    const float* bq   = (const float*)d_in[3];   // [EMB]
    const float* Ww   = (const float*)d_in[4];   // [VOCAB, EMB]
    const float* bw   = (const float*)d_in[5];   // [VOCAB]
    float* out = (float*)d_out;                  // [VOCAB]

    float* ws      = (float*)d_ws;
    float* s       = ws;                         // VOCAB
    float* hraw    = ws + VOCAB;                 // EMB
    float* gsum    = ws + VOCAB + EMB;           // 1
    float* logits  = ws + VOCAB + EMB + 16;      // VOCAB

    // zero the accumulators (s, hraw, gsum)
    hipMemsetAsync(d_ws, 0, (size_t)(VOCAB + EMB + 16) * sizeof(float), stream);

    dim3 g1((VOCAB + 255) / 256, 8);
    k_colsum<<<g1, 256, 0, stream>>>(X, s);

    dim3 g2(32, EMB);
    k_hidden<<<g2, 256, 0, stream>>>(Wq, s, hraw);

    int g3 = (VOCAB + 15) / 16;
    k_logits<<<g3, 256, 0, stream>>>(Ww, bw, hraw, bq, lenp, logits, gsum);

    int g4 = (VOCAB + 255) / 256;
    k_finalize<<<g4, 256, 0, stream>>>(logits, gsum, out);
}

// Round 2
// 149.635 us; speedup vs baseline: 1.4990x; 1.4990x over previous
//
#include <hip/hip_runtime.h>
#include <math.h>

#define VOCAB 50257
#define EMB   128
#define CTX   200
#define SLABS 4
#define ROWS_PER_SLAB (CTX / SLABS)          // 50
#define NT ((VOCAB + 15) / 16)               // 3142 row-tiles of 16
#define K3_BLOCKS 786

// ---------------- K1: spart[slab][v] = sum of 50 rows of X ------------------
// grid (197, SLABS), block 256. Plain stores, no atomics.
__global__ void k_colsum(const float* __restrict__ X, float* __restrict__ spart) {
    int v = blockIdx.x * 256 + threadIdx.x;
    if (v >= VOCAB) return;
    const float* p = X + (size_t)(blockIdx.y * ROWS_PER_SLAB) * VOCAB + v;
    float a0 = 0.f, a1 = 0.f, a2 = 0.f, a3 = 0.f, a4 = 0.f;
#pragma unroll
    for (int i = 0; i < ROWS_PER_SLAB / 5; ++i) {   // 10 iters x 5 rows
        a0 += p[0 * (size_t)VOCAB];
        a1 += p[1 * (size_t)VOCAB];
        a2 += p[2 * (size_t)VOCAB];
        a3 += p[3 * (size_t)VOCAB];
        a4 += p[4 * (size_t)VOCAB];
        p += 5 * (size_t)VOCAB;
    }
    spart[(size_t)blockIdx.y * VOCAB + v] = ((a0 + a1) + (a2 + a3)) + a4;
}

// ---------------- K2: hraw[e] = sum_v s[v] * Wq[e,v],  s = sum of slabs -----
// grid (32, 128), block 256. One atomic per block into 128 distinct addresses.
__global__ void k_hidden(const float* __restrict__ Wq, const float* __restrict__ spart,
                         float* __restrict__ hraw) {
    int e = blockIdx.y;
    const float* row = Wq + (size_t)e * VOCAB;
    float acc = 0.f;
    int stride = gridDim.x * blockDim.x;            // 8192
    for (int v = blockIdx.x * blockDim.x + threadIdx.x; v < VOCAB; v += stride) {
        float sv = spart[v] + spart[VOCAB + v] + spart[2 * VOCAB + v] + spart[3 * VOCAB + v];
        acc += sv * row[v];
    }
    for (int off = 32; off > 0; off >>= 1) acc += __shfl_down(acc, off, 64);
    __shared__ float wsum[4];
    int lane = threadIdx.x & 63, wid = threadIdx.x >> 6;
    if (lane == 0) wsum[wid] = acc;
    __syncthreads();
    if (threadIdx.x == 0)
        atomicAdd(&hraw[e], (wsum[0] + wsum[1]) + (wsum[2] + wsum[3]));
}

// ---------------- K3: logits + per-block exp partial (NO atomics) -----------
// grid K3_BLOCKS, block 256. Grid-stride over 16-row tiles; 16 lanes per row,
// two float4 loads per lane (512 B contiguous per row). One partial store/block.
__global__ void k_logits(const float* __restrict__ Ww, const float* __restrict__ bw,
                         const float* __restrict__ hraw, const float* __restrict__ bq,
                         const int* __restrict__ lenp,
                         float* __restrict__ logits, float* __restrict__ partials) {
    __shared__ float h[EMB];
    __shared__ float wsum[4];
    if (threadIdx.x < EMB) {
        float len = (float)lenp[0];
        h[threadIdx.x] = (hraw[threadIdx.x] + (float)CTX * bq[threadIdx.x]) / len;
    }
    __syncthreads();

    int group = threadIdx.x >> 4;                   // 0..15: row within tile
    int c     = threadIdx.x & 15;                   // lane within row
    float eacc = 0.f;

    for (int tile = blockIdx.x; tile < NT; tile += gridDim.x) {
        int v = tile * 16 + group;
        float acc = 0.f;
        if (v < VOCAB) {
            const float4* row = (const float4*)(Ww + (size_t)v * EMB);
            float4 w0 = row[c * 2];
            float4 w1 = row[c * 2 + 1];
            const float* hp = h + c * 8;
            acc = w0.x * hp[0] + w0.y * hp[1] + w0.z * hp[2] + w0.w * hp[3]
                + w1.x * hp[4] + w1.y * hp[5] + w1.z * hp[6] + w1.w * hp[7];
        }
        acc += __shfl_xor(acc, 1, 64);
        acc += __shfl_xor(acc, 2, 64);
        acc += __shfl_xor(acc, 4, 64);
        acc += __shfl_xor(acc, 8, 64);
        if (v < VOCAB && c == 0) {
            float lg = acc + bw[v];
            logits[v] = lg;
            eacc += expf(lg);
        }
    }

    for (int off = 32; off > 0; off >>= 1) eacc += __shfl_down(eacc, off, 64);
    int lane = threadIdx.x & 63, wid = threadIdx.x >> 6;
    if (lane == 0) wsum[wid] = eacc;
    __syncthreads();
    if (threadIdx.x == 0)
        partials[blockIdx.x] = (wsum[0] + wsum[1]) + (wsum[2] + wsum[3]);
}

// ---------------- K3b: logZ = log(sum partials), single block ---------------
__global__ void k_reduce(const float* __restrict__ partials, float* __restrict__ logZ) {
    float acc = 0.f;
    for (int i = threadIdx.x; i < K3_BLOCKS; i += blockDim.x) acc += partials[i];
    for (int off = 32; off > 0; off >>= 1) acc += __shfl_down(acc, off, 64);
    __shared__ float wsum[4];
    int lane = threadIdx.x & 63, wid = threadIdx.x >> 6;
    if (lane == 0) wsum[wid] = acc;
    __syncthreads();
    if (threadIdx.x == 0)
        logZ[0] = logf((wsum[0] + wsum[1]) + (wsum[2] + wsum[3]));
}

// ---------------- K4: out[v] = logits[v] - logZ -----------------------------
__global__ void k_finalize(const float* __restrict__ logits,
                           const float* __restrict__ logZ,
                           float* __restrict__ out) {
    int v = blockIdx.x * blockDim.x + threadIdx.x;
    if (v < VOCAB) out[v] = logits[v] - logZ[0];
}

extern "C" void kernel_launch(void* const* d_in, const int* in_sizes, int n_in,
                              void* d_out, int out_size, void* d_ws, size_t ws_size,
                              hipStream_t stream) {
    const float* X    = (const float*)d_in[0];   // [CTX, VOCAB]
    const int*   lenp = (const int*)d_in[1];     // scalar 200
    const float* Wq   = (const float*)d_in[2];   // [EMB, VOCAB]
    const float* bq   = (const float*)d_in[3];   // [EMB]
    const float* Ww   = (const float*)d_in[4];   // [VOCAB, EMB]
    const float* bw   = (const float*)d_in[5];   // [VOCAB]
    float* out = (float*)d_out;                  // [VOCAB]

    // Workspace layout (floats):
    //   [0,128)            hraw   (needs zero: k_hidden atomics)
    //   [128]              logZ
    //   [160, 160+786)     partials
    //   [1184, 1184+4*V)   spart (4 slabs)
    //   logits ALIASES spart slab 0 — safe: k_hidden (reader of spart) completes
    //   before k_logits (writer of logits) in stream order.
    float* ws       = (float*)d_ws;
    float* hraw     = ws;
    float* logZ     = ws + 128;
    float* partials = ws + 160;
    float* spart    = ws + 1184;
    float* logits   = spart;

    hipMemsetAsync(hraw, 0, 160 * sizeof(float), stream);

    dim3 g1((VOCAB + 255) / 256, SLABS);
    k_colsum<<<g1, 256, 0, stream>>>(X, spart);

    dim3 g2(32, EMB);
    k_hidden<<<g2, 256, 0, stream>>>(Wq, spart, hraw);

    k_logits<<<K3_BLOCKS, 256, 0, stream>>>(Ww, bw, hraw, bq, lenp, logits, partials);

    k_reduce<<<1, 256, 0, stream>>>(partials, logZ);

    k_finalize<<<(VOCAB + 255) / 256, 256, 0, stream>>>(logits, logZ, out);
}

// Round 3
// 132.671 us; speedup vs baseline: 1.6906x; 1.1279x over previous
//
#include <hip/hip_runtime.h>
#include <math.h>

#define VOCAB 50257
#define EMB   128
#define CTX   200
#define SLABS 4
#define ROWS_PER_SLAB (CTX / SLABS)          // 50
#define NT ((VOCAB + 15) / 16)               // 3142 row-tiles of 16
#define K3_BLOCKS 786
#define HCHUNKS 32                           // k_hidden grid.x

// ---------------- K1: spart[slab][v] = sum of 50 rows of X ------------------
// grid (197, SLABS), block 256. Plain stores, no atomics.
__global__ void k_colsum(const float* __restrict__ X, float* __restrict__ spart) {
    int v = blockIdx.x * 256 + threadIdx.x;
    if (v >= VOCAB) return;
    const float* p = X + (size_t)(blockIdx.y * ROWS_PER_SLAB) * VOCAB + v;
    float a0 = 0.f, a1 = 0.f, a2 = 0.f, a3 = 0.f, a4 = 0.f;
#pragma unroll
    for (int i = 0; i < ROWS_PER_SLAB / 5; ++i) {   // 10 iters x 5 rows
        a0 += p[0 * (size_t)VOCAB];
        a1 += p[1 * (size_t)VOCAB];
        a2 += p[2 * (size_t)VOCAB];
        a3 += p[3 * (size_t)VOCAB];
        a4 += p[4 * (size_t)VOCAB];
        p += 5 * (size_t)VOCAB;
    }
    spart[(size_t)blockIdx.y * VOCAB + v] = ((a0 + a1) + (a2 + a3)) + a4;
}

// ---------------- K2: hpart[chunk][e] = partial of sum_v s[v]*Wq[e,v] -------
// grid (HCHUNKS, 128), block 256. Plain store per block — no atomics, no memset.
__global__ void k_hidden(const float* __restrict__ Wq, const float* __restrict__ spart,
                         float* __restrict__ hpart) {
    int e = blockIdx.y;
    const float* row = Wq + (size_t)e * VOCAB;
    float acc = 0.f;
    int stride = gridDim.x * blockDim.x;            // 8192
    for (int v = blockIdx.x * blockDim.x + threadIdx.x; v < VOCAB; v += stride) {
        float sv = spart[v] + spart[VOCAB + v] + spart[2 * VOCAB + v] + spart[3 * VOCAB + v];
        acc += sv * row[v];
    }
    for (int off = 32; off > 0; off >>= 1) acc += __shfl_down(acc, off, 64);
    __shared__ float wsum[4];
    int lane = threadIdx.x & 63, wid = threadIdx.x >> 6;
    if (lane == 0) wsum[wid] = acc;
    __syncthreads();
    if (threadIdx.x == 0)
        hpart[blockIdx.x * EMB + e] = (wsum[0] + wsum[1]) + (wsum[2] + wsum[3]);
}

// ---------------- K3: logits + per-block exp partial (no atomics) -----------
// grid K3_BLOCKS, block 256. h built per-block from the 32 hpart chunks (L2).
// 16 lanes per row v, two float4 loads per lane (512 B contiguous per row).
__global__ void k_logits(const float* __restrict__ Ww, const float* __restrict__ bw,
                         const float* __restrict__ hpart, const float* __restrict__ bq,
                         const int* __restrict__ lenp,
                         float* __restrict__ logits, float* __restrict__ partials) {
    __shared__ float h[EMB];
    __shared__ float wsum[4];
    if (threadIdx.x < EMB) {
        float len = (float)lenp[0];
        float hr = 0.f;
#pragma unroll
        for (int c = 0; c < HCHUNKS; ++c) hr += hpart[c * EMB + threadIdx.x];
        h[threadIdx.x] = (hr + (float)CTX * bq[threadIdx.x]) / len;
    }
    __syncthreads();

    int group = threadIdx.x >> 4;                   // 0..15: row within tile
    int c     = threadIdx.x & 15;                   // lane within row
    float eacc = 0.f;

    for (int tile = blockIdx.x; tile < NT; tile += gridDim.x) {
        int v = tile * 16 + group;
        float acc = 0.f;
        if (v < VOCAB) {
            const float4* row = (const float4*)(Ww + (size_t)v * EMB);
            float4 w0 = row[c * 2];
            float4 w1 = row[c * 2 + 1];
            const float* hp = h + c * 8;
            acc = w0.x * hp[0] + w0.y * hp[1] + w0.z * hp[2] + w0.w * hp[3]
                + w1.x * hp[4] + w1.y * hp[5] + w1.z * hp[6] + w1.w * hp[7];
        }
        acc += __shfl_xor(acc, 1, 64);
        acc += __shfl_xor(acc, 2, 64);
        acc += __shfl_xor(acc, 4, 64);
        acc += __shfl_xor(acc, 8, 64);
        if (v < VOCAB && c == 0) {
            float lg = acc + bw[v];
            logits[v] = lg;
            eacc += expf(lg);
        }
    }

    for (int off = 32; off > 0; off >>= 1) eacc += __shfl_down(eacc, off, 64);
    int lane = threadIdx.x & 63, wid = threadIdx.x >> 6;
    if (lane == 0) wsum[wid] = eacc;
    __syncthreads();
    if (threadIdx.x == 0)
        partials[blockIdx.x] = (wsum[0] + wsum[1]) + (wsum[2] + wsum[3]);
}

// ---------------- K4: out[v] = logits[v] - log(sum partials) ----------------
// Each block redundantly reduces the 786 partials (3 KB, L2-hot) — this folds
// the old single-block k_reduce into the finalize pass, saving a dispatch.
__global__ void k_finalize(const float* __restrict__ logits,
                           const float* __restrict__ partials,
                           float* __restrict__ out) {
    __shared__ float wsum[4];
    __shared__ float lz;
    float acc = 0.f;
    for (int i = threadIdx.x; i < K3_BLOCKS; i += 256) acc += partials[i];
    for (int off = 32; off > 0; off >>= 1) acc += __shfl_down(acc, off, 64);
    int lane = threadIdx.x & 63, wid = threadIdx.x >> 6;
    if (lane == 0) wsum[wid] = acc;
    __syncthreads();
    if (threadIdx.x == 0)
        lz = logf((wsum[0] + wsum[1]) + (wsum[2] + wsum[3]));
    __syncthreads();
    int v = blockIdx.x * 256 + threadIdx.x;
    if (v < VOCAB) out[v] = logits[v] - lz;
}

extern "C" void kernel_launch(void* const* d_in, const int* in_sizes, int n_in,
                              void* d_out, int out_size, void* d_ws, size_t ws_size,
                              hipStream_t stream) {
    const float* X    = (const float*)d_in[0];   // [CTX, VOCAB]
    const int*   lenp = (const int*)d_in[1];     // scalar 200
    const float* Wq   = (const float*)d_in[2];   // [EMB, VOCAB]
    const float* bq   = (const float*)d_in[3];   // [EMB]
    const float* Ww   = (const float*)d_in[4];   // [VOCAB, EMB]
    const float* bw   = (const float*)d_in[5];   // [VOCAB]
    float* out = (float*)d_out;                  // [VOCAB]

    // Workspace layout (floats) — all plain stores, nothing needs zeroing:
    //   [0, 4096)                    hpart [32][128]
    //   [4096, 4096+786)             partials
    //   [8192, 8192+4*V)             spart (4 slabs)
    //   logits aliases spart slab 0 — safe: k_hidden (last reader of spart)
    //   completes before k_logits (writer of logits) in stream order.
    float* ws       = (float*)d_ws;
    float* hpart    = ws;
    float* partials = ws + 4096;
    float* spart    = ws + 8192;
    float* logits   = spart;

    dim3 g1((VOCAB + 255) / 256, SLABS);
    k_colsum<<<g1, 256, 0, stream>>>(X, spart);

    dim3 g2(HCHUNKS, EMB);
    k_hidden<<<g2, 256, 0, stream>>>(Wq, spart, hpart);

    k_logits<<<K3_BLOCKS, 256, 0, stream>>>(Ww, bw, hpart, bq, lenp, logits, partials);

    k_finalize<<<(VOCAB + 255) / 256, 256, 0, stream>>>(logits, partials, out);
}